// Round 8
// baseline (232.695 us; speedup 1.0000x reference)
//
#include <hip/hip_runtime.h>
#include <hip/hip_bf16.h>

namespace {

constexpr int kB = 512, kT = 512, kN = 128, kM = 64, kU = 64;
constexpr int WST = 68;   // w1 stage row stride (u32): 68 mod 32 = 4 -> bank-spread

typedef __attribute__((ext_vector_type(8))) short short8;    // bf16x8 MFMA frag
typedef __attribute__((ext_vector_type(16))) float f32x16;   // 32x32 MFMA acc

__device__ __forceinline__ unsigned rne16(float v) {
  unsigned u = __float_as_uint(v);
  return (u + 0x7fffu + ((u >> 16) & 1u)) >> 16;
}
__device__ __forceinline__ float fb16(unsigned h) { return __uint_as_float(h << 16); }

// packed LDS element: hi bf16 in top 16 bits, lo bf16 in bottom 16 (r5/r6-verified)
__device__ __forceinline__ unsigned pack_hl(float v) {
  unsigned h = rne16(v);
  unsigned l = rne16(v - fb16(h));
  return (h << 16) | (l & 0xffffu);
}

__device__ __forceinline__ float fast_tanh(float x) {
  return 1.0f - 2.0f / (__expf(2.0f * x) + 1.0f);
}

union FragU { unsigned u[4]; short8 s; };

// 8 packed u32 (k-order) -> hi/lo frags (r5/r6-verified element order).
__device__ __forceinline__ void unpack_hl(const unsigned* p, short8& hi, short8& lo) {
  FragU H, L;
#pragma unroll
  for (int j = 0; j < 4; ++j) {
    unsigned a = p[2 * j], b = p[2 * j + 1];
    H.u[j] = (a >> 16) | (b & 0xffff0000u);
    L.u[j] = (a & 0xffffu) | (b << 16);
  }
  hi = H.s; lo = L.s;
}

// 8 f32 -> hi/lo frags directly (r7-verified element order).
__device__ __forceinline__ void pack8(const float* v, short8& hi, short8& lo) {
  FragU H, L;
#pragma unroll
  for (int jj = 0; jj < 4; ++jj) {
    float v0 = v[2 * jj], v1 = v[2 * jj + 1];
    unsigned h0 = rne16(v0), h1 = rne16(v1);
    unsigned l0 = rne16(v0 - fb16(h0)), l1 = rne16(v1 - fb16(h1));
    H.u[jj] = h0 | (h1 << 16);
    L.u[jj] = l0 | (l1 << 16);
  }
  hi = H.s; lo = L.s;
}

// Kernel 1: raw scores sn[b,n] -> d_ws. Grid = B x 2 (n-halves), 256 threads.
// Wave w: m = w&1 (n in [64h+32m, +32)), ug = w>>1 (u in [32ug, +32)).
// A-frags: direct global b32 loads + in-register pack (r7-verified mapping).
// B-frags: w1 chunk staged packed in LDS, stride 68 (r5-verified mapping).
__global__ __launch_bounds__(256, 4) void score_kernel(
    const float* __restrict__ x,    // (B,T,N)
    const float* __restrict__ hs,   // (B,M)
    const float* __restrict__ cs,   // (B,M)
    const float* __restrict__ w1,   // (T,U)
    const float* __restrict__ w1b,  // (U)
    const float* __restrict__ w2,   // (2M,U)
    const float* __restrict__ w2b,  // (U)
    const float* __restrict__ vk,   // (U,1)
    float* __restrict__ sn_out)     // (B,N) raw scores, f32 (d_ws)
{
  __shared__ unsigned wst[kU * WST];   // 17408 B
  __shared__ float qpart[4][kU];
  __shared__ float qpfull[kU];
  __shared__ float sred[2][kU];

  const int bh = blockIdx.x;
  const int b = bh >> 1;
  const int h = bh & 1;
  const int tid = threadIdx.x;
  const int l = tid & 63;
  const int w = tid >> 6;
  const int ln = l & 31;
  const int kh = l >> 5;
  const int m = w & 1;
  const int ug = w >> 1;
  const int nA = 64 * h + 32 * m + ln;   // this lane's A row (n)
  const int u = 32 * ug + ln;            // this lane's B col (u)

  // ---- q_proj partials: 256 threads, 32 k-terms each ----
  {
    const int uu = tid & 63, kg = tid >> 6;
    float a0 = 0.f;
#pragma unroll
    for (int j = 0; j < 32; ++j) {
      int k = kg * 32 + j;
      float qv = (k < kM) ? hs[(size_t)b * kM + k] : cs[(size_t)b * kM + (k - kM)];
      a0 = fmaf(qv, w2[k * kU + uu], a0);
    }
    qpart[kg][uu] = a0;
  }

  f32x16 acc;
#pragma unroll
  for (int i = 0; i < 16; ++i) acc[i] = 0.f;

  // ---- K loop: 8 chunks of 64 t ----
  for (int tc = 0; tc < kT; tc += 64) {
    __syncthreads();   // prev chunk reads done (also covers qpart, 1st iter)
    // stage w1[tc..tc+63][0..63] packed: row = u, one row per lane
    {
      const int row = tid & 63;
      const int cb = (tid >> 6) * 16;
      unsigned pw[16];
#pragma unroll
      for (int j = 0; j < 16; ++j)
        pw[j] = pack_hl(w1[(size_t)(tc + cb + j) * kU + row]);
#pragma unroll
      for (int jj = 0; jj < 4; ++jj)
        *(uint4*)&wst[row * WST + cb + 4 * jj] =
            make_uint4(pw[4 * jj], pw[4 * jj + 1], pw[4 * jj + 2], pw[4 * jj + 3]);
    }
    __syncthreads();

#pragma unroll
    for (int ss = 0; ss < 4; ++ss) {
      // A: 8 coalesced b32 loads (consecutive n across 32 lanes)
      float rA[8];
#pragma unroll
      for (int j = 0; j < 8; ++j)
        rA[j] = x[((size_t)b * kT + tc + 16 * ss + 8 * kh + j) * kN + nA];
      short8 ah, al;
      pack8(rA, ah, al);

      unsigned rb[8];
      const unsigned* pb = &wst[u * WST + 16 * ss + 8 * kh];
      *(uint4*)&rb[0] = *(const uint4*)pb;
      *(uint4*)&rb[4] = *(const uint4*)(pb + 4);
      short8 bh, bl;
      unpack_hl(rb, bh, bl);

      acc = __builtin_amdgcn_mfma_f32_32x32x16_bf16(ah, bh, acc, 0, 0, 0);
      acc = __builtin_amdgcn_mfma_f32_32x32x16_bf16(ah, bl, acc, 0, 0, 0);
      acc = __builtin_amdgcn_mfma_f32_32x32x16_bf16(al, bh, acc, 0, 0, 0);
    }
  }
  __syncthreads();

  // ---- qpfull ----
  if (tid < kU) {
    float v = w2b[tid] + w1b[tid];
#pragma unroll
    for (int g = 0; g < 4; ++g) v += qpart[g][tid];
    qpfull[tid] = v;
  }
  __syncthreads();

  // ---- epilogue: tanh + *v, reduce over this wave's 32 u-lanes ----
  {
    const float qp = qpfull[u];
    const float vu = vk[u];
    float pr[16];
#pragma unroll
    for (int r = 0; r < 16; ++r)
      pr[r] = fast_tanh(acc[r] + qp) * vu;
#pragma unroll
    for (int off = 1; off < 32; off <<= 1)
#pragma unroll
      for (int r = 0; r < 16; ++r)
        pr[r] += __shfl_xor(pr[r], off);
    if (ln == 0) {
      // C/D row map (m74/m101): n_local = 32m + (r&3) + 8*(r>>2) + 4*kh
#pragma unroll
      for (int r = 0; r < 16; ++r)
        sred[ug][32 * m + (r & 3) + 8 * (r >> 2) + 4 * kh] = pr[r];
    }
  }
  __syncthreads();
  if (tid < 64)
    sn_out[(size_t)b * kN + 64 * h + tid] = sred[0][tid] + sred[1][tid];
}

// Kernel 2: softmax (per-block, redundant x4 — trivial) + context.
// Grid = B x 4 segments, 256 threads, quad-per-row (r5-verified body).
__global__ __launch_bounds__(256) void context_kernel(
    const float* __restrict__ x,
    const float* __restrict__ sn_in,   // (B,N) raw scores (d_ws)
    float* __restrict__ ctx,           // (B,T)
    float* __restrict__ aw_out)        // (B,1,N)
{
  __shared__ float sm[kN];
  __shared__ float aw[kN];
  const int b = blockIdx.x >> 2;
  const int seg = blockIdx.x & 3;
  if (threadIdx.x < kN) sm[threadIdx.x] = sn_in[(size_t)b * kN + threadIdx.x];
  __syncthreads();

  if (threadIdx.x < 64) {   // wave 0: softmax over 128 (v_bias shift cancels)
    float s0 = sm[threadIdx.x], s1 = sm[threadIdx.x + 64];
    float mx = fmaxf(s0, s1);
#pragma unroll
    for (int off = 32; off > 0; off >>= 1) mx = fmaxf(mx, __shfl_xor(mx, off));
    float e0 = __expf(s0 - mx), e1 = __expf(s1 - mx);
    float se = e0 + e1;
#pragma unroll
    for (int off = 32; off > 0; off >>= 1) se += __shfl_xor(se, off);
    float inv = 1.0f / se;
    float a0 = e0 * inv, a1 = e1 * inv;
    aw[threadIdx.x] = a0;
    aw[threadIdx.x + 64] = a1;
    if (seg == 0) {
      aw_out[(size_t)b * kN + threadIdx.x] = a0;
      aw_out[(size_t)b * kN + threadIdx.x + 64] = a1;
    }
  }
  __syncthreads();

  const int lr = threadIdx.x & 3;
  const int row = threadIdx.x >> 2;   // 0..63
#pragma unroll
  for (int rg = 0; rg < 2; ++rg) {
    const int r = seg * 128 + rg * 64 + row;
    const float4* xp = (const float4*)(x + ((size_t)b * kT + r) * kN);
    float a = 0.f;
#pragma unroll
    for (int k = 0; k < 8; ++k) {
      int i = lr + k * 4;              // 32 float4 per row, quad-covered
      float4 v = xp[i];
      const float* wa = &aw[i * 4];
      a = fmaf(v.x, wa[0], a);
      a = fmaf(v.y, wa[1], a);
      a = fmaf(v.z, wa[2], a);
      a = fmaf(v.w, wa[3], a);
    }
    a += __shfl_xor(a, 1);
    a += __shfl_xor(a, 2);
    if (lr == 0) ctx[(size_t)b * kT + r] = a;
  }
}

}  // namespace

extern "C" void kernel_launch(void* const* d_in, const int* in_sizes, int n_in,
                              void* d_out, int out_size, void* d_ws, size_t ws_size,
                              hipStream_t stream) {
  const float* x   = (const float*)d_in[0];
  const float* hs  = (const float*)d_in[1];
  const float* cs  = (const float*)d_in[2];
  const float* w1  = (const float*)d_in[3];
  const float* w1b = (const float*)d_in[4];
  const float* w2  = (const float*)d_in[5];
  const float* w2b = (const float*)d_in[6];
  const float* vk  = (const float*)d_in[7];

  float* out = (float*)d_out;
  float* ctx = out;                      // context_vector (B,T)
  float* awo = out + (size_t)kB * kT;    // attention_weights (B,1,N)
  float* sn  = (float*)d_ws;             // (B,N) raw scores, 256 KB

  hipLaunchKernelGGL(score_kernel, dim3(kB * 2), dim3(256), 0, stream,
                     x, hs, cs, w1, w1b, w2, w2b, vk, sn);
  hipLaunchKernelGGL(context_kernel, dim3(kB * 4), dim3(256), 0, stream,
                     x, sn, ctx, awo);
}